// Round 1
// 209.383 us; speedup vs baseline: 1.1286x; 1.1286x over previous
//
#include <hip/hip_runtime.h>
#include <hip/hip_bf16.h>

typedef unsigned short u16;
typedef unsigned int u32;
typedef __attribute__((ext_vector_type(8))) short bf16x8;
typedef __attribute__((ext_vector_type(4))) float f32x4;

#define MFMA_BF16(a, b, c) __builtin_amdgcn_mfma_f32_16x16x32_bf16((a), (b), (c), 0, 0, 0)

__device__ __forceinline__ u16 f2bf(float f) {
    u32 u;
    __builtin_memcpy(&u, &f, 4);
    u += 0x7fffu + ((u >> 16) & 1u);
    return (u16)(u >> 16);
}

__device__ __forceinline__ void glds16(const void* g, void* l) {
    __builtin_amdgcn_global_load_lds(
        (__attribute__((address_space(1))) void*)(g),
        (__attribute__((address_space(3))) void*)(l),
        16, 0, 0);
}

// ---------------------------------------------------------------------------
// f32 -> bf16 elementwise convert; 8 elements per thread.
// ---------------------------------------------------------------------------
__global__ __launch_bounds__(256) void f32_to_bf16(const float* __restrict__ in,
                                                   u16* __restrict__ out) {
    const int i = blockIdx.x * 256 + threadIdx.x;
    const float4* p = (const float4*)in;
    float4 a = p[i * 2], b = p[i * 2 + 1];
    ushort4 lo, hi;
    lo.x = f2bf(a.x); lo.y = f2bf(a.y); lo.z = f2bf(a.z); lo.w = f2bf(a.w);
    hi.x = f2bf(b.x); hi.y = f2bf(b.y); hi.z = f2bf(b.z); hi.w = f2bf(b.w);
    *(ushort4*)&out[i * 8] = lo;
    *(ushort4*)&out[i * 8 + 4] = hi;
}

// ---------------------------------------------------------------------------
// Weight transpose + f32->bf16: in f32 [K][N] -> out bf16 [N][K]
// grid: (N/64, K/64), block 256
// ---------------------------------------------------------------------------
__global__ __launch_bounds__(256) void transpose_k(const float* __restrict__ in,
                                                   u16* __restrict__ out,
                                                   int K, int N) {
    __shared__ u16 tl[64][68];
    const int tid = threadIdx.x;
    const int n0 = blockIdx.x * 64, k0 = blockIdx.y * 64;
    #pragma unroll
    for (int it = 0; it < 4; ++it) {
        int idx = tid + it * 256;
        int r = idx >> 4, c4 = (idx & 15) * 4;
        float4 v = *(const float4*)&in[(size_t)(k0 + r) * N + n0 + c4];
        tl[r][c4 + 0] = f2bf(v.x); tl[r][c4 + 1] = f2bf(v.y);
        tl[r][c4 + 2] = f2bf(v.z); tl[r][c4 + 3] = f2bf(v.w);
    }
    __syncthreads();
    #pragma unroll
    for (int it = 0; it < 4; ++it) {
        int idx = tid + it * 256;
        int r = idx >> 4, c4 = (idx & 15) * 4;
        ushort4 v;
        v.x = tl[c4 + 0][r]; v.y = tl[c4 + 1][r];
        v.z = tl[c4 + 2][r]; v.w = tl[c4 + 3][r];
        *(ushort4*)&out[(size_t)(n0 + r) * K + k0 + c4] = v;
    }
}

// ---------------------------------------------------------------------------
// bf16 transpose for V: in [BH][T=2048][D=64] -> out [BH][D=64][T=2048].
// grid (T/64, BH), block 256.
// ---------------------------------------------------------------------------
__global__ __launch_bounds__(256) void transpose_v(const u16* __restrict__ in,
                                                   u16* __restrict__ out) {
    __shared__ u16 tl[64][72];
    const int tid = threadIdx.x;
    const int t0 = blockIdx.x * 64;
    const int bh = blockIdx.y;
    const u16* ip = in + (size_t)bh * 2048 * 64;
    u16* op = out + (size_t)bh * 64 * 2048;
    #pragma unroll
    for (int it = 0; it < 2; ++it) {
        int idx = tid + it * 256;
        int r = idx >> 3, c8 = (idx & 7) * 8;
        *(bf16x8*)&tl[r][c8] = *(const bf16x8*)&ip[(size_t)(t0 + r) * 64 + c8];
    }
    __syncthreads();
    #pragma unroll
    for (int it = 0; it < 2; ++it) {
        int idx = tid + it * 256;
        int d = idx >> 3, c8 = (idx & 7) * 8;
        ushort4 v0, v1;
        v0.x = tl[c8 + 0][d]; v0.y = tl[c8 + 1][d];
        v0.z = tl[c8 + 2][d]; v0.w = tl[c8 + 3][d];
        v1.x = tl[c8 + 4][d]; v1.y = tl[c8 + 5][d];
        v1.z = tl[c8 + 6][d]; v1.w = tl[c8 + 7][d];
        *(ushort4*)&op[(size_t)d * 2048 + t0 + c8] = v0;
        *(ushort4*)&op[(size_t)d * 2048 + t0 + c8 + 4] = v1;
    }
}

// ---------------------------------------------------------------------------
// m97-style gemm_bt: C[M,N] = A[M,K]*BT[N,K]^T + bias, K=1024, bf16 A/BT.
// mode 0: scatter bf16 k,q,v ALL natural [B,H,T,D]; K output (reg 0) is
//         pre-scaled by log2(e)/sqrt(64) so attn softmax needs no multiply.
// mode 1: f32 outf[M,1024].
// ---------------------------------------------------------------------------
__global__ __launch_bounds__(256) void gemm_bt(const u16* __restrict__ A,
                                               const u16* __restrict__ BT,
                                               const float* __restrict__ bias,
                                               u16* __restrict__ out0,
                                               u16* __restrict__ out1,
                                               u16* __restrict__ out2,
                                               float* __restrict__ outf,
                                               int mode) {
    __shared__ u16 As[128 * 32];
    __shared__ u16 Bs[128 * 32];
    const int tid = threadIdx.x;
    const int w = tid >> 6, lane = tid & 63;
    const int c = lane & 15, qd = lane >> 4;
    const int wm = (w >> 1) * 64, wn = (w & 1) * 64;
    const int bm = blockIdx.x * 128, bn = blockIdx.y * 128;
    const int K = 1024;

    f32x4 acc[4][4];
    #pragma unroll
    for (int mt = 0; mt < 4; ++mt)
        #pragma unroll
        for (int nt = 0; nt < 4; ++nt)
            acc[mt][nt] = (f32x4){0.f, 0.f, 0.f, 0.f};

    const u16* aP = A + (size_t)(bm + (tid >> 2)) * K + (tid & 3) * 8;
    const u16* bP = BT + (size_t)(bn + (tid >> 2)) * K + (tid & 3) * 8;
    u16* lA0 = &As[tid * 8];
    u16* lA1 = &As[2048 + tid * 8];
    u16* lB0 = &Bs[tid * 8];
    u16* lB1 = &Bs[2048 + tid * 8];

    for (int kk = 0; kk < K; kk += 32) {
        glds16(aP + kk, lA0);
        glds16(aP + kk + 64 * K, lA1);
        glds16(bP + kk, lB0);
        glds16(bP + kk + 64 * K, lB1);
        __syncthreads();
        bf16x8 af[4], bfr[4];
        #pragma unroll
        for (int mt = 0; mt < 4; ++mt)
            af[mt] = *(const bf16x8*)&As[(wm + mt * 16 + c) * 32 + qd * 8];
        #pragma unroll
        for (int nt = 0; nt < 4; ++nt)
            bfr[nt] = *(const bf16x8*)&Bs[(wn + nt * 16 + c) * 32 + qd * 8];
        #pragma unroll
        for (int mt = 0; mt < 4; ++mt)
            #pragma unroll
            for (int nt = 0; nt < 4; ++nt)
                acc[mt][nt] = MFMA_BF16(af[mt], bfr[nt], acc[mt][nt]);
        __syncthreads();
    }

    #pragma unroll
    for (int nt = 0; nt < 4; ++nt) {
        const int coln = bn + wn + nt * 16 + c;
        const float bv = bias[coln];
        const int reg = coln >> 10;
        const int nr = coln & 1023;
        const int hh = nr >> 6;
        const int dd = nr & 63;
        // fold attention scale log2(e)/sqrt(64) into K (reg 0) at projection
        const float kscl = (mode == 0 && reg == 0) ? 0.18033688f : 1.0f;
        u16* dst = (reg == 0) ? out0 : (reg == 1) ? out1 : out2;
        #pragma unroll
        for (int mt = 0; mt < 4; ++mt) {
            #pragma unroll
            for (int r = 0; r < 4; ++r) {
                const int row = bm + wm + mt * 16 + qd * 4 + r;
                const float ov = (acc[mt][nt][r] + bv) * kscl;
                if (mode == 0) {
                    const int b = row >> 11, t = row & 2047;
                    dst[((b * 16 + hh) * 2048 + t) * 64 + dd] = f2bf(ov);
                } else {
                    outf[(size_t)row * 1024 + coln] = ov;
                }
            }
        }
    }
}

// ---------------------------------------------------------------------------
// MFMA flash attention v4. wei = K@Q^T (K rows = queries). K pre-scaled.
// 512 blocks x 256 thr (4 waves): i-blocks now 64 rows (wave owns 16 rows),
// paired (p, 31-p) -> uniform 33 j-tiles/block; 2 blocks/CU = 8 waves/CU
// (v3 was 256 blocks = 1 block/CU = 1 wave/SIMD -> every barrier/VALU dep
// stalled the SIMD; MfmaUtil 8.9%, Occupancy 10.5%).
// blockIdx decode groups 4 bh per XCD (linear%8 round-robin) so Q/V working
// set per XCD ~3MB < 4MB L2 (v3 FETCH 71.5MB = ~4x Q/V refetch from HBM).
// Q/V tiles double-buffered via glds16; XOR-swizzled [64][64] LDS; K-frags
// direct global->regs; static-max softmax (scale folded into K upstream).
// LDS: 2*8K(Q) + 2*8K(V) + 9.2K(P) + 0.25K = ~42 KB -> 2 blocks/CU.
// ---------------------------------------------------------------------------
__global__ __launch_bounds__(256, 2) void attn_kernel(const u16* __restrict__ kbuf,
                                                      const u16* __restrict__ qbuf,
                                                      const u16* __restrict__ vtbuf,
                                                      u16* __restrict__ outb) {
    __shared__ __align__(16) u16 Qb[2][64 * 64];
    __shared__ __align__(16) u16 Vb[2][64 * 64];
    __shared__ __align__(16) u16 Ps[4][16 * 72];
    __shared__ float red[4][16];

    const int tid = threadIdx.x;
    const int w = tid >> 6, lane = tid & 63;
    const int c = lane & 15, qd = lane >> 4;
    // flat 512 blocks: xcd = id%8 hosts bh in [xcd*4, xcd*4+4) for L2 locality
    const int f = blockIdx.x;
    const int g = f >> 3;
    const int bh = (f & 7) * 4 + (g & 3);
    const int pr = g >> 2;              // pair index 0..15
    const u16* kp = kbuf + (size_t)bh * (2048 * 64);
    const u16* qp = qbuf + (size_t)bh * (2048 * 64);
    const u16* vp = vtbuf + (size_t)bh * (64 * 2048);
    const int b = bh >> 4, hh = bh & 15;
    u16* op = outb + (size_t)b * (2048 * 1024) + hh * 64;
    const f32x4 zero4 = {0.f, 0.f, 0.f, 0.f};

    // staging geometry: thread covers slots (w*128+lane) and (+64); 8 rows/8 col8
    const int slot0 = w * 128 + lane;
    const int slot1 = slot0 + 64;
    const int r0 = slot0 >> 3, r1 = slot1 >> 3;            // r1 = r0 + 8
    const int c8g = ((lane & 7) ^ ((lane >> 3) & 7)) * 8;  // swizzled src col
    const int swz = (c & 7);                               // read-side xor key

    #pragma unroll
    for (int phase = 0; phase < 2; ++phase) {
        const int ib = (phase == 0) ? pr : 31 - pr;        // 64-row i-block
        const int nj = ib + 1;
        const int iw = ib * 64 + w * 16;                   // wave's 16 i-rows

        // K fragments direct from global (2 KB/wave, read once per phase)
        bf16x8 kf[2];
        #pragma unroll
        for (int kt = 0; kt < 2; ++kt)
            kf[kt] = *(const bf16x8*)&kp[(size_t)(iw + c) * 64 + kt * 32 + qd * 8];

        f32x4 oacc[4];
        #pragma unroll
        for (int nt = 0; nt < 4; ++nt)
            oacc[nt] = zero4;
        float l_lane = 0.f;

        // prologue: stage tile 0 into buffer 0
        glds16(qp + (size_t)r0 * 64 + c8g, &Qb[0][slot0 * 8]);
        glds16(qp + (size_t)r1 * 64 + c8g, &Qb[0][slot1 * 8]);
        glds16(vp + (size_t)r0 * 2048 + c8g, &Vb[0][slot0 * 8]);
        glds16(vp + (size_t)r1 * 2048 + c8g, &Vb[0][slot1 * 8]);
        __syncthreads();

        for (int jj = 0; jj < nj; ++jj) {
            const int cur = jj & 1;
            if (jj + 1 < nj) {              // async-prefetch next tile
                const int jn = (jj + 1) * 64;
                const int nb = cur ^ 1;
                glds16(qp + (size_t)(jn + r0) * 64 + c8g, &Qb[nb][slot0 * 8]);
                glds16(qp + (size_t)(jn + r1) * 64 + c8g, &Qb[nb][slot1 * 8]);
                glds16(vp + (size_t)r0 * 2048 + jn + c8g, &Vb[nb][slot0 * 8]);
                glds16(vp + (size_t)r1 * 2048 + jn + c8g, &Vb[nb][slot1 * 8]);
            }
            const int j0 = jj * 64;

            // S^T[j][i]: A = Q rows j (4 jt), B = kf (wave's 16 i-rows)
            bf16x8 qf[4][2];
            #pragma unroll
            for (int jt = 0; jt < 4; ++jt)
                #pragma unroll
                for (int kt = 0; kt < 2; ++kt)
                    qf[jt][kt] = *(const bf16x8*)&Qb[cur][(jt * 16 + c) * 64 + (((kt * 4 + qd) ^ swz) << 3)];
            f32x4 sacc[4];
            #pragma unroll
            for (int jt = 0; jt < 4; ++jt) {
                f32x4 s0 = zero4;
                s0 = MFMA_BF16(qf[jt][0], kf[0], s0);
                s0 = MFMA_BF16(qf[jt][1], kf[1], s0);
                sacc[jt] = s0;
            }

            if (j0 + 63 > iw) {   // causal: valid iff j <= i
                #pragma unroll
                for (int jt = 0; jt < 4; ++jt)
                    #pragma unroll
                    for (int r = 0; r < 4; ++r) {
                        int j = j0 + jt * 16 + qd * 4 + r;
                        int i = iw + c;
                        if (j > i) sacc[jt][r] = -3.0e38f;
                    }
            }

            // static-max softmax (scale pre-folded into K); P to wave-private LDS
            #pragma unroll
            for (int jt = 0; jt < 4; ++jt) {
                float p0 = exp2f(sacc[jt][0]);
                float p1 = exp2f(sacc[jt][1]);
                float p2 = exp2f(sacc[jt][2]);
                float p3 = exp2f(sacc[jt][3]);
                l_lane += (p0 + p1) + (p2 + p3);
                ushort4 pk;
                pk.x = f2bf(p0); pk.y = f2bf(p1);
                pk.z = f2bf(p2); pk.w = f2bf(p3);
                *(ushort4*)&Ps[w][c * 72 + jt * 16 + qd * 4] = pk;
            }

            // O[i][d] += P[i][j] * V[j][d]
            #pragma unroll
            for (int kt = 0; kt < 2; ++kt) {
                bf16x8 pf = *(const bf16x8*)&Ps[w][c * 72 + kt * 32 + qd * 8];
                #pragma unroll
                for (int nt = 0; nt < 4; ++nt) {
                    bf16x8 vf = *(const bf16x8*)&Vb[cur][(nt * 16 + c) * 64 + (((kt * 4 + qd) ^ swz) << 3)];
                    oacc[nt] = MFMA_BF16(pf, vf, oacc[nt]);
                }
            }
            __syncthreads();   // drains prefetch glds; all reads of cur done
        }

        // epilogue: reduce l over qd, redistribute per-row, write out
        float l = l_lane;
        l += __shfl_xor(l, 16);
        l += __shfl_xor(l, 32);
        red[w][c] = l;
        #pragma unroll
        for (int r = 0; r < 4; ++r) {
            const int irow = iw + qd * 4 + r;
            const float inv = 1.0f / red[w][qd * 4 + r];
            #pragma unroll
            for (int nt = 0; nt < 4; ++nt)
                op[(size_t)irow * 1024 + nt * 16 + c] = f2bf(oacc[nt][r] * inv);
        }
        __syncthreads();   // phase done before restaging buffers
    }
}

// ---------------------------------------------------------------------------
// ws plan (peak 40 MiB):
//   kbuf@0 (8M) qbuf@8M (8M) vnat@16M (8M) vtr@24M (8M) wt_attn@32M (6M)
//   abuf@32M (8M, wt_attn dead) wt_proj@16M (2M, vnat dead)
//   xb (bf16 x) staged in d_out (f32 out = 16 MB); dead before proj gemm.
// ---------------------------------------------------------------------------
extern "C" void kernel_launch(void* const* d_in, const int* in_sizes, int n_in,
                              void* d_out, int out_size, void* d_ws, size_t ws_size,
                              hipStream_t stream) {
    const void *px = nullptr, *paw = nullptr, *pab = nullptr, *ppw = nullptr, *ppb = nullptr;
    for (int i = 0; i < n_in; ++i) {
        switch (in_sizes[i]) {
            case 4194304: px  = d_in[i]; break;  // x [2,2048,1024] f32
            case 3145728: paw = d_in[i]; break;  // c_attn_w [1024,3072] f32
            case 3072:    pab = d_in[i]; break;  // c_attn_b f32
            case 1048576: ppw = d_in[i]; break;  // c_proj_w [1024,1024] f32
            case 1024:    ppb = d_in[i]; break;  // c_proj_b f32
        }
    }
    if (!px || !paw || !pab || !ppw || !ppb) return;

    char* ws = (char*)d_ws;
    u16* kbuf    = (u16*)(ws);                 // [2,16,2048,64]  8 MB (pre-scaled)
    u16* qbuf    = (u16*)(ws + 8388608);       // [2,16,2048,64]  8 MB
    u16* vnat    = (u16*)(ws + 16777216);      // [2,16,2048,64]  8 MB (natural)
    u16* vtr     = (u16*)(ws + 25165824);      // [2,16,64,2048]  8 MB (transposed)
    u16* wt_attn = (u16*)(ws + 33554432);      // [3072,1024]     6 MB
    u16* abuf    = (u16*)(ws + 33554432);      // [4096,1024]     8 MB (wt_attn dead)
    u16* wt_proj = (u16*)(ws + 16777216);      // [1024,1024]     2 MB (vnat dead)
    float* out   = (float*)d_out;              // [4096,1024] f32
    u16* xb      = (u16*)d_out;                // bf16 x staged in d_out

    f32_to_bf16<<<2048, 256, 0, stream>>>((const float*)px, xb);
    transpose_k<<<dim3(48, 16), 256, 0, stream>>>((const float*)paw, wt_attn, 1024, 3072);
    gemm_bt<<<dim3(32, 24), 256, 0, stream>>>(xb, wt_attn, (const float*)pab,
                                              kbuf, qbuf, vnat, nullptr, 0);
    transpose_v<<<dim3(32, 32), 256, 0, stream>>>(vnat, vtr);
    attn_kernel<<<dim3(512), 256, 0, stream>>>(kbuf, qbuf, vtr, abuf);
    transpose_k<<<dim3(16, 16), 256, 0, stream>>>((const float*)ppw, wt_proj, 1024, 1024);
    gemm_bt<<<dim3(32, 8), 256, 0, stream>>>(abuf, wt_proj, (const float*)ppb,
                                             nullptr, nullptr, nullptr, out, 1);
}

// Round 2
// 190.837 us; speedup vs baseline: 1.2382x; 1.0972x over previous
//
#include <hip/hip_runtime.h>
#include <hip/hip_bf16.h>

typedef unsigned short u16;
typedef unsigned int u32;
typedef __attribute__((ext_vector_type(8))) short bf16x8;
typedef __attribute__((ext_vector_type(4))) float f32x4;

#define MFMA_BF16(a, b, c) __builtin_amdgcn_mfma_f32_16x16x32_bf16((a), (b), (c), 0, 0, 0)

__device__ __forceinline__ u16 f2bf(float f) {
    u32 u;
    __builtin_memcpy(&u, &f, 4);
    u += 0x7fffu + ((u >> 16) & 1u);
    return (u16)(u >> 16);
}

__device__ __forceinline__ void glds16(const void* g, void* l) {
    __builtin_amdgcn_global_load_lds(
        (__attribute__((address_space(1))) void*)(g),
        (__attribute__((address_space(3))) void*)(l),
        16, 0, 0);
}

// ---------------------------------------------------------------------------
// f32 -> bf16 elementwise convert; 8 elements per thread.
// ---------------------------------------------------------------------------
__global__ __launch_bounds__(256) void f32_to_bf16(const float* __restrict__ in,
                                                   u16* __restrict__ out) {
    const int i = blockIdx.x * 256 + threadIdx.x;
    const float4* p = (const float4*)in;
    float4 a = p[i * 2], b = p[i * 2 + 1];
    ushort4 lo, hi;
    lo.x = f2bf(a.x); lo.y = f2bf(a.y); lo.z = f2bf(a.z); lo.w = f2bf(a.w);
    hi.x = f2bf(b.x); hi.y = f2bf(b.y); hi.z = f2bf(b.z); hi.w = f2bf(b.w);
    *(ushort4*)&out[i * 8] = lo;
    *(ushort4*)&out[i * 8 + 4] = hi;
}

// ---------------------------------------------------------------------------
// Weight transpose + f32->bf16: in f32 [K][N] -> out bf16 [N][K]
// grid: (N/64, K/64), block 256
// ---------------------------------------------------------------------------
__global__ __launch_bounds__(256) void transpose_k(const float* __restrict__ in,
                                                   u16* __restrict__ out,
                                                   int K, int N) {
    __shared__ u16 tl[64][68];
    const int tid = threadIdx.x;
    const int n0 = blockIdx.x * 64, k0 = blockIdx.y * 64;
    #pragma unroll
    for (int it = 0; it < 4; ++it) {
        int idx = tid + it * 256;
        int r = idx >> 4, c4 = (idx & 15) * 4;
        float4 v = *(const float4*)&in[(size_t)(k0 + r) * N + n0 + c4];
        tl[r][c4 + 0] = f2bf(v.x); tl[r][c4 + 1] = f2bf(v.y);
        tl[r][c4 + 2] = f2bf(v.z); tl[r][c4 + 3] = f2bf(v.w);
    }
    __syncthreads();
    #pragma unroll
    for (int it = 0; it < 4; ++it) {
        int idx = tid + it * 256;
        int r = idx >> 4, c4 = (idx & 15) * 4;
        ushort4 v;
        v.x = tl[c4 + 0][r]; v.y = tl[c4 + 1][r];
        v.z = tl[c4 + 2][r]; v.w = tl[c4 + 3][r];
        *(ushort4*)&out[(size_t)(n0 + r) * K + k0 + c4] = v;
    }
}

// ---------------------------------------------------------------------------
// bf16 transpose for V: reads V band from natural kqv [4096][3072]
// (cols 2048 + h*64 ..) -> out [BH][D=64][T=2048]. grid (T/64, BH), block 256.
// ---------------------------------------------------------------------------
__global__ __launch_bounds__(256) void transpose_v(const u16* __restrict__ kqv,
                                                   u16* __restrict__ out) {
    __shared__ u16 tl[64][72];
    const int tid = threadIdx.x;
    const int t0 = blockIdx.x * 64;
    const int bh = blockIdx.y;
    const int b = bh >> 4, hh = bh & 15;
    const u16* ip = kqv + (size_t)b * 2048 * 3072 + 2048 + hh * 64;
    u16* op = out + (size_t)bh * 64 * 2048;
    #pragma unroll
    for (int it = 0; it < 2; ++it) {
        int idx = tid + it * 256;
        int r = idx >> 3, c8 = (idx & 7) * 8;
        *(bf16x8*)&tl[r][c8] = *(const bf16x8*)&ip[(size_t)(t0 + r) * 3072 + c8];
    }
    __syncthreads();
    #pragma unroll
    for (int it = 0; it < 2; ++it) {
        int idx = tid + it * 256;
        int d = idx >> 3, c8 = (idx & 7) * 8;
        ushort4 v0, v1;
        v0.x = tl[c8 + 0][d]; v0.y = tl[c8 + 1][d];
        v0.z = tl[c8 + 2][d]; v0.w = tl[c8 + 3][d];
        v1.x = tl[c8 + 4][d]; v1.y = tl[c8 + 5][d];
        v1.z = tl[c8 + 6][d]; v1.w = tl[c8 + 7][d];
        *(ushort4*)&op[(size_t)d * 2048 + t0 + c8] = v0;
        *(ushort4*)&op[(size_t)d * 2048 + t0 + c8 + 4] = v1;
    }
}

// ---------------------------------------------------------------------------
// QKV GEMM, 2-phase double-buffered (T3-minimum): C[4096,3072] natural bf16.
// BM=BN=128, BK=32, 4 waves 2x2. Next K-tile staged via glds16 BEFORE the
// current tile's ds_read+MFMA; ONE barrier/iter (vmcnt drain hidden under
// compute) vs old stage->drain->compute->barrier (2 barriers, exposed drain).
// LDS chunk swizzle: LDS[row][j] = global[row][j ^ ((row>>1)&3)] via
// pre-swizzled glds16 SOURCE (linear dest, rule 21); read side same XOR
// -> 8-way bank conflict becomes 2-way (free). K cols (<1024) pre-scaled by
// log2(e)/sqrt(64). LDS 32 KB -> grid 768 = 3 blocks/CU.
// ---------------------------------------------------------------------------
__global__ __launch_bounds__(256) void gemm_qkv(const u16* __restrict__ A,
                                                const u16* __restrict__ BT,
                                                const float* __restrict__ bias,
                                                u16* __restrict__ out) {
    __shared__ u16 As[2][128 * 32];
    __shared__ u16 Bs[2][128 * 32];
    const int tid = threadIdx.x;
    const int w = tid >> 6, lane = tid & 63;
    const int c = lane & 15, qd = lane >> 4;
    const int wm = (w >> 1) * 64, wn = (w & 1) * 64;
    const int bm = blockIdx.x * 128, bn = blockIdx.y * 128;
    const int K = 1024;

    f32x4 acc[4][4];
    #pragma unroll
    for (int mt = 0; mt < 4; ++mt)
        #pragma unroll
        for (int nt = 0; nt < 4; ++nt)
            acc[mt][nt] = (f32x4){0.f, 0.f, 0.f, 0.f};

    // staging: thread -> (row = tid>>2 [+64], src chunk swizzled by (row>>1)&3)
    const int srow = tid >> 2;
    const int schk8 = ((tid & 3) ^ ((tid >> 3) & 3)) * 8;
    const u16* aP = A + (size_t)(bm + srow) * K + schk8;
    const u16* bP = BT + (size_t)(bn + srow) * K + schk8;
    const int rk = (c >> 1) & 3;          // read-side xor key

    // prologue: stage K-tile 0 into buffer 0
    glds16(aP, &As[0][tid * 8]);
    glds16(aP + 64 * K, &As[0][2048 + tid * 8]);
    glds16(bP, &Bs[0][tid * 8]);
    glds16(bP + 64 * K, &Bs[0][2048 + tid * 8]);
    __syncthreads();

    for (int kk = 0; kk < K; kk += 32) {
        const int cur = (kk >> 5) & 1;
        if (kk + 32 < K) {               // prefetch next K-tile into other buf
            const int nb = cur ^ 1;
            glds16(aP + kk + 32, &As[nb][tid * 8]);
            glds16(aP + kk + 32 + 64 * K, &As[nb][2048 + tid * 8]);
            glds16(bP + kk + 32, &Bs[nb][tid * 8]);
            glds16(bP + kk + 32 + 64 * K, &Bs[nb][2048 + tid * 8]);
        }
        bf16x8 af[4], bfr[4];
        #pragma unroll
        for (int mt = 0; mt < 4; ++mt)
            af[mt] = *(const bf16x8*)&As[cur][(wm + mt * 16 + c) * 32 + ((qd ^ rk) << 3)];
        #pragma unroll
        for (int nt = 0; nt < 4; ++nt)
            bfr[nt] = *(const bf16x8*)&Bs[cur][(wn + nt * 16 + c) * 32 + ((qd ^ rk) << 3)];
        #pragma unroll
        for (int mt = 0; mt < 4; ++mt)
            #pragma unroll
            for (int nt = 0; nt < 4; ++nt)
                acc[mt][nt] = MFMA_BF16(af[mt], bfr[nt], acc[mt][nt]);
        __syncthreads();                 // drains prefetch vmcnt + read lgkm
    }

    #pragma unroll
    for (int nt = 0; nt < 4; ++nt) {
        const int coln = bn + wn + nt * 16 + c;
        const float bv = bias[coln];
        // fold attention scale log2(e)/sqrt(64) into K (cols < 1024)
        const float kscl = (coln < 1024) ? 0.18033688f : 1.0f;
        #pragma unroll
        for (int mt = 0; mt < 4; ++mt)
            #pragma unroll
            for (int r = 0; r < 4; ++r) {
                const int row = bm + wm + mt * 16 + qd * 4 + r;
                out[(size_t)row * 3072 + coln] = f2bf((acc[mt][nt][r] + bv) * kscl);
            }
    }
}

// ---------------------------------------------------------------------------
// Proj GEMM: C[4096,1024] f32 = A[4096,1024]*BT[1024,1024]^T + bias.
// BM=128, BN=64 -> grid 32x16 = 512 blocks = 2 blocks/CU (old 128x128 grid
// was 256 blocks = 1 block/CU, latency-exposed). 4 waves 4Mx1N, acc[2][4].
// Same dbuf + swizzle structure as gemm_qkv. LDS 24 KB.
// ---------------------------------------------------------------------------
__global__ __launch_bounds__(256) void gemm_proj(const u16* __restrict__ A,
                                                 const u16* __restrict__ BT,
                                                 const float* __restrict__ bias,
                                                 float* __restrict__ outf) {
    __shared__ u16 As[2][128 * 32];
    __shared__ u16 Bs[2][64 * 32];
    const int tid = threadIdx.x;
    const int w = tid >> 6, lane = tid & 63;
    const int c = lane & 15, qd = lane >> 4;
    const int wm = w * 32;
    const int bm = blockIdx.x * 128, bn = blockIdx.y * 64;
    const int K = 1024;

    f32x4 acc[2][4];
    #pragma unroll
    for (int mt = 0; mt < 2; ++mt)
        #pragma unroll
        for (int nt = 0; nt < 4; ++nt)
            acc[mt][nt] = (f32x4){0.f, 0.f, 0.f, 0.f};

    const int srow = tid >> 2;
    const int schk8 = ((tid & 3) ^ ((tid >> 3) & 3)) * 8;
    const u16* aP = A + (size_t)(bm + srow) * K + schk8;
    const u16* bP = BT + (size_t)(bn + srow) * K + schk8;
    const int rk = (c >> 1) & 3;

    glds16(aP, &As[0][tid * 8]);
    glds16(aP + 64 * K, &As[0][2048 + tid * 8]);
    glds16(bP, &Bs[0][tid * 8]);
    __syncthreads();

    for (int kk = 0; kk < K; kk += 32) {
        const int cur = (kk >> 5) & 1;
        if (kk + 32 < K) {
            const int nb = cur ^ 1;
            glds16(aP + kk + 32, &As[nb][tid * 8]);
            glds16(aP + kk + 32 + 64 * K, &As[nb][2048 + tid * 8]);
            glds16(bP + kk + 32, &Bs[nb][tid * 8]);
        }
        bf16x8 af[2], bfr[4];
        #pragma unroll
        for (int mt = 0; mt < 2; ++mt)
            af[mt] = *(const bf16x8*)&As[cur][(wm + mt * 16 + c) * 32 + ((qd ^ rk) << 3)];
        #pragma unroll
        for (int nt = 0; nt < 4; ++nt)
            bfr[nt] = *(const bf16x8*)&Bs[cur][(nt * 16 + c) * 32 + ((qd ^ rk) << 3)];
        #pragma unroll
        for (int mt = 0; mt < 2; ++mt)
            #pragma unroll
            for (int nt = 0; nt < 4; ++nt)
                acc[mt][nt] = MFMA_BF16(af[mt], bfr[nt], acc[mt][nt]);
        __syncthreads();
    }

    #pragma unroll
    for (int nt = 0; nt < 4; ++nt) {
        const int coln = bn + nt * 16 + c;
        const float bv = bias[coln];
        #pragma unroll
        for (int mt = 0; mt < 2; ++mt)
            #pragma unroll
            for (int r = 0; r < 4; ++r) {
                const int row = bm + wm + mt * 16 + qd * 4 + r;
                outf[(size_t)row * 1024 + coln] = acc[mt][nt][r] + bv;
            }
    }
}

// ---------------------------------------------------------------------------
// MFMA flash attention v5. wei = K@Q^T (K rows = queries). K pre-scaled.
// K,Q read directly from natural kqv [4096][3072] (row stride 3072; each
// lane's 16B stays contiguous, so glds16/frag loads are unaffected).
// 512 blocks x 256 thr: 64-row i-blocks paired (p, 31-p) -> 33 j-tiles,
// 2 blocks/CU = 8 waves/CU. XCD-grouped bh decode for L2 locality.
// Q/V tiles double-buffered via glds16; XOR-swizzled [64][64] LDS; K-frags
// direct global->regs; static-max softmax. LDS ~42 KB.
// ---------------------------------------------------------------------------
__global__ __launch_bounds__(256, 2) void attn_kernel(const u16* __restrict__ kqv,
                                                      const u16* __restrict__ vtbuf,
                                                      u16* __restrict__ outb) {
    __shared__ __align__(16) u16 Qb[2][64 * 64];
    __shared__ __align__(16) u16 Vb[2][64 * 64];
    __shared__ __align__(16) u16 Ps[4][16 * 72];
    __shared__ float red[4][16];

    const int tid = threadIdx.x;
    const int w = tid >> 6, lane = tid & 63;
    const int c = lane & 15, qd = lane >> 4;
    // flat 512 blocks: xcd = id%8 hosts bh in [xcd*4, xcd*4+4) for L2 locality
    const int f = blockIdx.x;
    const int g = f >> 3;
    const int bh = (f & 7) * 4 + (g & 3);
    const int pr = g >> 2;              // pair index 0..15
    const int b = bh >> 4, hh = bh & 15;
    const u16* kp = kqv + (size_t)b * 2048 * 3072 + hh * 64;          // k band
    const u16* qp = kqv + (size_t)b * 2048 * 3072 + 1024 + hh * 64;   // q band
    const u16* vp = vtbuf + (size_t)bh * (64 * 2048);
    u16* op = outb + (size_t)b * (2048 * 1024) + hh * 64;
    const f32x4 zero4 = {0.f, 0.f, 0.f, 0.f};

    // staging geometry: thread covers slots (w*128+lane) and (+64); 8 rows/8 col8
    const int slot0 = w * 128 + lane;
    const int slot1 = slot0 + 64;
    const int r0 = slot0 >> 3, r1 = slot1 >> 3;            // r1 = r0 + 8
    const int c8g = ((lane & 7) ^ ((lane >> 3) & 7)) * 8;  // swizzled src col
    const int swz = (c & 7);                               // read-side xor key

    #pragma unroll
    for (int phase = 0; phase < 2; ++phase) {
        const int ib = (phase == 0) ? pr : 31 - pr;        // 64-row i-block
        const int nj = ib + 1;
        const int iw = ib * 64 + w * 16;                   // wave's 16 i-rows

        // K fragments direct from global (2 KB/wave, read once per phase)
        bf16x8 kf[2];
        #pragma unroll
        for (int kt = 0; kt < 2; ++kt)
            kf[kt] = *(const bf16x8*)&kp[(size_t)(iw + c) * 3072 + kt * 32 + qd * 8];

        f32x4 oacc[4];
        #pragma unroll
        for (int nt = 0; nt < 4; ++nt)
            oacc[nt] = zero4;
        float l_lane = 0.f;

        // prologue: stage tile 0 into buffer 0
        glds16(qp + (size_t)r0 * 3072 + c8g, &Qb[0][slot0 * 8]);
        glds16(qp + (size_t)r1 * 3072 + c8g, &Qb[0][slot1 * 8]);
        glds16(vp + (size_t)r0 * 2048 + c8g, &Vb[0][slot0 * 8]);
        glds16(vp + (size_t)r1 * 2048 + c8g, &Vb[0][slot1 * 8]);
        __syncthreads();

        for (int jj = 0; jj < nj; ++jj) {
            const int cur = jj & 1;
            if (jj + 1 < nj) {              // async-prefetch next tile
                const int jn = (jj + 1) * 64;
                const int nb = cur ^ 1;
                glds16(qp + (size_t)(jn + r0) * 3072 + c8g, &Qb[nb][slot0 * 8]);
                glds16(qp + (size_t)(jn + r1) * 3072 + c8g, &Qb[nb][slot1 * 8]);
                glds16(vp + (size_t)r0 * 2048 + jn + c8g, &Vb[nb][slot0 * 8]);
                glds16(vp + (size_t)r1 * 2048 + jn + c8g, &Vb[nb][slot1 * 8]);
            }
            const int j0 = jj * 64;

            // S^T[j][i]: A = Q rows j (4 jt), B = kf (wave's 16 i-rows)
            bf16x8 qf[4][2];
            #pragma unroll
            for (int jt = 0; jt < 4; ++jt)
                #pragma unroll
                for (int kt = 0; kt < 2; ++kt)
                    qf[jt][kt] = *(const bf16x8*)&Qb[cur][(jt * 16 + c) * 64 + (((kt * 4 + qd) ^ swz) << 3)];
            f32x4 sacc[4];
            #pragma unroll
            for (int jt = 0; jt < 4; ++jt) {
                f32x4 s0 = zero4;
                s0 = MFMA_BF16(qf[jt][0], kf[0], s0);
                s0 = MFMA_BF16(qf[jt][1], kf[1], s0);
                sacc[jt] = s0;
            }

            if (j0 + 63 > iw) {   // causal: valid iff j <= i
                #pragma unroll
                for (int jt = 0; jt < 4; ++jt)
                    #pragma unroll
                    for (int r = 0; r < 4; ++r) {
                        int j = j0 + jt * 16 + qd * 4 + r;
                        int i = iw + c;
                        if (j > i) sacc[jt][r] = -3.0e38f;
                    }
            }

            // static-max softmax (scale pre-folded into K); P to wave-private LDS
            #pragma unroll
            for (int jt = 0; jt < 4; ++jt) {
                float p0 = exp2f(sacc[jt][0]);
                float p1 = exp2f(sacc[jt][1]);
                float p2 = exp2f(sacc[jt][2]);
                float p3 = exp2f(sacc[jt][3]);
                l_lane += (p0 + p1) + (p2 + p3);
                ushort4 pk;
                pk.x = f2bf(p0); pk.y = f2bf(p1);
                pk.z = f2bf(p2); pk.w = f2bf(p3);
                *(ushort4*)&Ps[w][c * 72 + jt * 16 + qd * 4] = pk;
            }

            // O[i][d] += P[i][j] * V[j][d]
            #pragma unroll
            for (int kt = 0; kt < 2; ++kt) {
                bf16x8 pf = *(const bf16x8*)&Ps[w][c * 72 + kt * 32 + qd * 8];
                #pragma unroll
                for (int nt = 0; nt < 4; ++nt) {
                    bf16x8 vf = *(const bf16x8*)&Vb[cur][(nt * 16 + c) * 64 + (((kt * 4 + qd) ^ swz) << 3)];
                    oacc[nt] = MFMA_BF16(pf, vf, oacc[nt]);
                }
            }
            __syncthreads();   // drains prefetch glds; all reads of cur done
        }

        // epilogue: reduce l over qd, redistribute per-row, write out
        float l = l_lane;
        l += __shfl_xor(l, 16);
        l += __shfl_xor(l, 32);
        red[w][c] = l;
        #pragma unroll
        for (int r = 0; r < 4; ++r) {
            const int irow = iw + qd * 4 + r;
            const float inv = 1.0f / red[w][qd * 4 + r];
            #pragma unroll
            for (int nt = 0; nt < 4; ++nt)
                op[(size_t)irow * 1024 + nt * 16 + c] = f2bf(oacc[nt][r] * inv);
        }
        __syncthreads();   // phase done before restaging buffers
    }
}

// ---------------------------------------------------------------------------
// ws plan (peak 40 MiB):
//   kqv@0 (24M, natural [4096][3072] bf16)  vtr@24M (8M)
//   wt_attn@32M (6M, dead after gemm_qkv)  abuf@32M (8M, after wt_attn dead)
//   wt_proj@0 (2M, kqv dead after attn)
//   xb (bf16 x) staged in d_out (f32 out = 16 MB); dead before proj gemm.
// ---------------------------------------------------------------------------
extern "C" void kernel_launch(void* const* d_in, const int* in_sizes, int n_in,
                              void* d_out, int out_size, void* d_ws, size_t ws_size,
                              hipStream_t stream) {
    const void *px = nullptr, *paw = nullptr, *pab = nullptr, *ppw = nullptr, *ppb = nullptr;
    for (int i = 0; i < n_in; ++i) {
        switch (in_sizes[i]) {
            case 4194304: px  = d_in[i]; break;  // x [2,2048,1024] f32
            case 3145728: paw = d_in[i]; break;  // c_attn_w [1024,3072] f32
            case 3072:    pab = d_in[i]; break;  // c_attn_b f32
            case 1048576: ppw = d_in[i]; break;  // c_proj_w [1024,1024] f32
            case 1024:    ppb = d_in[i]; break;  // c_proj_b f32
        }
    }
    if (!px || !paw || !pab || !ppw || !ppb) return;

    char* ws = (char*)d_ws;
    u16* kqv     = (u16*)(ws);                 // [4096,3072] bf16  24 MB
    u16* vtr     = (u16*)(ws + 25165824);      // [2,16,64,2048]     8 MB
    u16* wt_attn = (u16*)(ws + 33554432);      // [3072,1024]        6 MB
    u16* abuf    = (u16*)(ws + 33554432);      // [4096,1024] bf16   8 MB (wt_attn dead)
    u16* wt_proj = (u16*)(ws);                 // [1024,1024]        2 MB (kqv dead)
    float* out   = (float*)d_out;              // [4096,1024] f32
    u16* xb      = (u16*)d_out;                // bf16 x staged in d_out

    f32_to_bf16<<<2048, 256, 0, stream>>>((const float*)px, xb);
    transpose_k<<<dim3(48, 16), 256, 0, stream>>>((const float*)paw, wt_attn, 1024, 3072);
    gemm_qkv<<<dim3(32, 24), 256, 0, stream>>>(xb, wt_attn, (const float*)pab, kqv);
    transpose_v<<<dim3(32, 32), 256, 0, stream>>>(kqv, vtr);
    attn_kernel<<<dim3(512), 256, 0, stream>>>(kqv, vtr, abuf);
    transpose_k<<<dim3(16, 16), 256, 0, stream>>>((const float*)ppw, wt_proj, 1024, 1024);
    gemm_proj<<<dim3(32, 16), 256, 0, stream>>>(abuf, wt_proj, (const float*)ppb, out);
}

// Round 3
// 182.804 us; speedup vs baseline: 1.2926x; 1.0439x over previous
//
#include <hip/hip_runtime.h>
#include <hip/hip_bf16.h>

typedef unsigned short u16;
typedef unsigned int u32;
typedef __attribute__((ext_vector_type(8))) short bf16x8;
typedef __attribute__((ext_vector_type(4))) float f32x4;

#define MFMA_BF16(a, b, c) __builtin_amdgcn_mfma_f32_16x16x32_bf16((a), (b), (c), 0, 0, 0)

__device__ __forceinline__ u16 f2bf(float f) {
    u32 u;
    __builtin_memcpy(&u, &f, 4);
    u += 0x7fffu + ((u >> 16) & 1u);
    return (u16)(u >> 16);
}

__device__ __forceinline__ void glds16(const void* g, void* l) {
    __builtin_amdgcn_global_load_lds(
        (__attribute__((address_space(1))) void*)(g),
        (__attribute__((address_space(3))) void*)(l),
        16, 0, 0);
}

// ---------------------------------------------------------------------------
// f32 -> bf16 elementwise convert; 8 elements per thread.
// ---------------------------------------------------------------------------
__global__ __launch_bounds__(256) void f32_to_bf16(const float* __restrict__ in,
                                                   u16* __restrict__ out) {
    const int i = blockIdx.x * 256 + threadIdx.x;
    const float4* p = (const float4*)in;
    float4 a = p[i * 2], b = p[i * 2 + 1];
    ushort4 lo, hi;
    lo.x = f2bf(a.x); lo.y = f2bf(a.y); lo.z = f2bf(a.z); lo.w = f2bf(a.w);
    hi.x = f2bf(b.x); hi.y = f2bf(b.y); hi.z = f2bf(b.z); hi.w = f2bf(b.w);
    *(ushort4*)&out[i * 8] = lo;
    *(ushort4*)&out[i * 8 + 4] = hi;
}

// ---------------------------------------------------------------------------
// Weight transpose + f32->bf16: in f32 [K][N] -> out bf16 [N][K]
// grid: (N/64, K/64), block 256
// ---------------------------------------------------------------------------
__global__ __launch_bounds__(256) void transpose_k(const float* __restrict__ in,
                                                   u16* __restrict__ out,
                                                   int K, int N) {
    __shared__ u16 tl[64][68];
    const int tid = threadIdx.x;
    const int n0 = blockIdx.x * 64, k0 = blockIdx.y * 64;
    #pragma unroll
    for (int it = 0; it < 4; ++it) {
        int idx = tid + it * 256;
        int r = idx >> 4, c4 = (idx & 15) * 4;
        float4 v = *(const float4*)&in[(size_t)(k0 + r) * N + n0 + c4];
        tl[r][c4 + 0] = f2bf(v.x); tl[r][c4 + 1] = f2bf(v.y);
        tl[r][c4 + 2] = f2bf(v.z); tl[r][c4 + 3] = f2bf(v.w);
    }
    __syncthreads();
    #pragma unroll
    for (int it = 0; it < 4; ++it) {
        int idx = tid + it * 256;
        int r = idx >> 4, c4 = (idx & 15) * 4;
        ushort4 v;
        v.x = tl[c4 + 0][r]; v.y = tl[c4 + 1][r];
        v.z = tl[c4 + 2][r]; v.w = tl[c4 + 3][r];
        *(ushort4*)&out[(size_t)(n0 + r) * K + k0 + c4] = v;
    }
}

// ---------------------------------------------------------------------------
// bf16 transpose for V: reads V band from natural kqv [4096][3072]
// (cols 2048 + h*64 ..) -> out [BH][D=64][T=2048]. grid (T/64, BH), block 256.
// ---------------------------------------------------------------------------
__global__ __launch_bounds__(256) void transpose_v(const u16* __restrict__ kqv,
                                                   u16* __restrict__ out) {
    __shared__ u16 tl[64][72];
    const int tid = threadIdx.x;
    const int t0 = blockIdx.x * 64;
    const int bh = blockIdx.y;
    const int b = bh >> 4, hh = bh & 15;
    const u16* ip = kqv + (size_t)b * 2048 * 3072 + 2048 + hh * 64;
    u16* op = out + (size_t)bh * 64 * 2048;
    #pragma unroll
    for (int it = 0; it < 2; ++it) {
        int idx = tid + it * 256;
        int r = idx >> 3, c8 = (idx & 7) * 8;
        *(bf16x8*)&tl[r][c8] = *(const bf16x8*)&ip[(size_t)(t0 + r) * 3072 + c8];
    }
    __syncthreads();
    #pragma unroll
    for (int it = 0; it < 2; ++it) {
        int idx = tid + it * 256;
        int d = idx >> 3, c8 = (idx & 7) * 8;
        ushort4 v0, v1;
        v0.x = tl[c8 + 0][d]; v0.y = tl[c8 + 1][d];
        v0.z = tl[c8 + 2][d]; v0.w = tl[c8 + 3][d];
        v1.x = tl[c8 + 4][d]; v1.y = tl[c8 + 5][d];
        v1.z = tl[c8 + 6][d]; v1.w = tl[c8 + 7][d];
        *(ushort4*)&op[(size_t)d * 2048 + t0 + c8] = v0;
        *(ushort4*)&op[(size_t)d * 2048 + t0 + c8 + 4] = v1;
    }
}

// ---------------------------------------------------------------------------
// QKV GEMM, 2-phase double-buffered (T3-minimum): C[4096,3072] natural bf16.
// BM=BN=128, BK=32, 4 waves 2x2. Next K-tile staged via glds16 BEFORE the
// current tile's ds_read+MFMA; ONE barrier/iter. LDS chunk swizzle via
// pre-swizzled glds16 SOURCE (linear dest, rule 21); read side same XOR.
// K cols (<1024) pre-scaled by log2(e)/sqrt(64). LDS 32 KB -> 3 blocks/CU.
// ---------------------------------------------------------------------------
__global__ __launch_bounds__(256) void gemm_qkv(const u16* __restrict__ A,
                                                const u16* __restrict__ BT,
                                                const float* __restrict__ bias,
                                                u16* __restrict__ out) {
    __shared__ u16 As[2][128 * 32];
    __shared__ u16 Bs[2][128 * 32];
    const int tid = threadIdx.x;
    const int w = tid >> 6, lane = tid & 63;
    const int c = lane & 15, qd = lane >> 4;
    const int wm = (w >> 1) * 64, wn = (w & 1) * 64;
    const int bm = blockIdx.x * 128, bn = blockIdx.y * 128;
    const int K = 1024;

    f32x4 acc[4][4];
    #pragma unroll
    for (int mt = 0; mt < 4; ++mt)
        #pragma unroll
        for (int nt = 0; nt < 4; ++nt)
            acc[mt][nt] = (f32x4){0.f, 0.f, 0.f, 0.f};

    // staging: thread -> (row = tid>>2 [+64], src chunk swizzled by (row>>1)&3)
    const int srow = tid >> 2;
    const int schk8 = ((tid & 3) ^ ((tid >> 3) & 3)) * 8;
    const u16* aP = A + (size_t)(bm + srow) * K + schk8;
    const u16* bP = BT + (size_t)(bn + srow) * K + schk8;
    const int rk = (c >> 1) & 3;          // read-side xor key

    // prologue: stage K-tile 0 into buffer 0
    glds16(aP, &As[0][tid * 8]);
    glds16(aP + 64 * K, &As[0][2048 + tid * 8]);
    glds16(bP, &Bs[0][tid * 8]);
    glds16(bP + 64 * K, &Bs[0][2048 + tid * 8]);
    __syncthreads();

    for (int kk = 0; kk < K; kk += 32) {
        const int cur = (kk >> 5) & 1;
        if (kk + 32 < K) {               // prefetch next K-tile into other buf
            const int nb = cur ^ 1;
            glds16(aP + kk + 32, &As[nb][tid * 8]);
            glds16(aP + kk + 32 + 64 * K, &As[nb][2048 + tid * 8]);
            glds16(bP + kk + 32, &Bs[nb][tid * 8]);
            glds16(bP + kk + 32 + 64 * K, &Bs[nb][2048 + tid * 8]);
        }
        bf16x8 af[4], bfr[4];
        #pragma unroll
        for (int mt = 0; mt < 4; ++mt)
            af[mt] = *(const bf16x8*)&As[cur][(wm + mt * 16 + c) * 32 + ((qd ^ rk) << 3)];
        #pragma unroll
        for (int nt = 0; nt < 4; ++nt)
            bfr[nt] = *(const bf16x8*)&Bs[cur][(wn + nt * 16 + c) * 32 + ((qd ^ rk) << 3)];
        #pragma unroll
        for (int mt = 0; mt < 4; ++mt)
            #pragma unroll
            for (int nt = 0; nt < 4; ++nt)
                acc[mt][nt] = MFMA_BF16(af[mt], bfr[nt], acc[mt][nt]);
        __syncthreads();                 // drains prefetch vmcnt + read lgkm
    }

    #pragma unroll
    for (int nt = 0; nt < 4; ++nt) {
        const int coln = bn + wn + nt * 16 + c;
        const float bv = bias[coln];
        // fold attention scale log2(e)/sqrt(64) into K (cols < 1024)
        const float kscl = (coln < 1024) ? 0.18033688f : 1.0f;
        #pragma unroll
        for (int mt = 0; mt < 4; ++mt)
            #pragma unroll
            for (int r = 0; r < 4; ++r) {
                const int row = bm + wm + mt * 16 + qd * 4 + r;
                out[(size_t)row * 3072 + coln] = f2bf((acc[mt][nt][r] + bv) * kscl);
            }
    }
}

// ---------------------------------------------------------------------------
// Proj GEMM: C[4096,1024] f32 = A[4096,1024]*BT[1024,1024]^T + bias.
// BM=128, BN=64 -> grid 32x16 = 512 blocks = 2 blocks/CU. 4 waves 4Mx1N.
// Same dbuf + swizzle structure as gemm_qkv. LDS 24 KB.
// ---------------------------------------------------------------------------
__global__ __launch_bounds__(256) void gemm_proj(const u16* __restrict__ A,
                                                 const u16* __restrict__ BT,
                                                 const float* __restrict__ bias,
                                                 float* __restrict__ outf) {
    __shared__ u16 As[2][128 * 32];
    __shared__ u16 Bs[2][64 * 32];
    const int tid = threadIdx.x;
    const int w = tid >> 6, lane = tid & 63;
    const int c = lane & 15, qd = lane >> 4;
    const int wm = w * 32;
    const int bm = blockIdx.x * 128, bn = blockIdx.y * 64;
    const int K = 1024;

    f32x4 acc[2][4];
    #pragma unroll
    for (int mt = 0; mt < 2; ++mt)
        #pragma unroll
        for (int nt = 0; nt < 4; ++nt)
            acc[mt][nt] = (f32x4){0.f, 0.f, 0.f, 0.f};

    const int srow = tid >> 2;
    const int schk8 = ((tid & 3) ^ ((tid >> 3) & 3)) * 8;
    const u16* aP = A + (size_t)(bm + srow) * K + schk8;
    const u16* bP = BT + (size_t)(bn + srow) * K + schk8;
    const int rk = (c >> 1) & 3;

    glds16(aP, &As[0][tid * 8]);
    glds16(aP + 64 * K, &As[0][2048 + tid * 8]);
    glds16(bP, &Bs[0][tid * 8]);
    __syncthreads();

    for (int kk = 0; kk < K; kk += 32) {
        const int cur = (kk >> 5) & 1;
        if (kk + 32 < K) {
            const int nb = cur ^ 1;
            glds16(aP + kk + 32, &As[nb][tid * 8]);
            glds16(aP + kk + 32 + 64 * K, &As[nb][2048 + tid * 8]);
            glds16(bP + kk + 32, &Bs[nb][tid * 8]);
        }
        bf16x8 af[2], bfr[4];
        #pragma unroll
        for (int mt = 0; mt < 2; ++mt)
            af[mt] = *(const bf16x8*)&As[cur][(wm + mt * 16 + c) * 32 + ((qd ^ rk) << 3)];
        #pragma unroll
        for (int nt = 0; nt < 4; ++nt)
            bfr[nt] = *(const bf16x8*)&Bs[cur][(nt * 16 + c) * 32 + ((qd ^ rk) << 3)];
        #pragma unroll
        for (int mt = 0; mt < 2; ++mt)
            #pragma unroll
            for (int nt = 0; nt < 4; ++nt)
                acc[mt][nt] = MFMA_BF16(af[mt], bfr[nt], acc[mt][nt]);
        __syncthreads();
    }

    #pragma unroll
    for (int nt = 0; nt < 4; ++nt) {
        const int coln = bn + nt * 16 + c;
        const float bv = bias[coln];
        #pragma unroll
        for (int mt = 0; mt < 2; ++mt)
            #pragma unroll
            for (int r = 0; r < 4; ++r) {
                const int row = bm + wm + mt * 16 + qd * 4 + r;
                outf[(size_t)row * 1024 + coln] = acc[mt][nt][r] + bv;
            }
    }
}

// ---------------------------------------------------------------------------
// MFMA flash attention v6. wei = K@Q^T (K rows = queries). K pre-scaled.
// 1024 blocks (32 ib x 32 bh), ONE 64-row i-block per block, dispatched
// LONGEST-FIRST (ib = 31 - (f>>5)) so greedy CU scheduling packs the tail.
// 3 blocks/CU resident (LDS 42.5KB, launch_bounds(256,3)) = 3 waves/SIMD
// (v5: pair structure capped grid at 512 = 2 blocks/CU, VALUBusy 44%,
// Occupancy 18% -> per-tile serial chain only half hidden).
// P pack via round-half-up + v_perm_b32: 3 VALU per 2 values (was 6).
// XCD-grouped bh decode; Q/V dbuf glds16; XOR-swizzled [64][64] LDS;
// K-frags direct global->regs; static-max softmax.
// ---------------------------------------------------------------------------
__global__ __launch_bounds__(256, 3) void attn_kernel(const u16* __restrict__ kqv,
                                                      const u16* __restrict__ vtbuf,
                                                      u16* __restrict__ outb) {
    __shared__ __align__(16) u16 Qb[2][64 * 64];
    __shared__ __align__(16) u16 Vb[2][64 * 64];
    __shared__ __align__(16) u16 Ps[4][16 * 72];
    __shared__ float red[4][16];

    const int tid = threadIdx.x;
    const int w = tid >> 6, lane = tid & 63;
    const int c = lane & 15, qd = lane >> 4;
    // decode: xcd = f&7 hosts bh in [xcd*4, xcd*4+4); ib descending in time
    const int f = blockIdx.x;
    const int bh = (f & 7) * 4 + ((f >> 3) & 3);
    const int ib = 31 - (f >> 5);       // longest blocks dispatch first
    const int b = bh >> 4, hh = bh & 15;
    const u16* kp = kqv + (size_t)b * 2048 * 3072 + hh * 64;          // k band
    const u16* qp = kqv + (size_t)b * 2048 * 3072 + 1024 + hh * 64;   // q band
    const u16* vp = vtbuf + (size_t)bh * (64 * 2048);
    u16* op = outb + (size_t)b * (2048 * 1024) + hh * 64;
    const f32x4 zero4 = {0.f, 0.f, 0.f, 0.f};

    // staging geometry: thread covers slots (w*128+lane) and (+64); 8 rows/8 col8
    const int slot0 = w * 128 + lane;
    const int slot1 = slot0 + 64;
    const int r0 = slot0 >> 3, r1 = slot1 >> 3;            // r1 = r0 + 8
    const int c8g = ((lane & 7) ^ ((lane >> 3) & 7)) * 8;  // swizzled src col
    const int swz = (c & 7);                               // read-side xor key

    const int nj = ib + 1;
    const int iw = ib * 64 + w * 16;                       // wave's 16 i-rows

    // K fragments direct from global (2 KB/wave, read once per block)
    bf16x8 kf[2];
    #pragma unroll
    for (int kt = 0; kt < 2; ++kt)
        kf[kt] = *(const bf16x8*)&kp[(size_t)(iw + c) * 3072 + kt * 32 + qd * 8];

    f32x4 oacc[4];
    #pragma unroll
    for (int nt = 0; nt < 4; ++nt)
        oacc[nt] = zero4;
    float l_lane = 0.f;

    // prologue: stage tile 0 into buffer 0
    glds16(qp + (size_t)r0 * 3072 + c8g, &Qb[0][slot0 * 8]);
    glds16(qp + (size_t)r1 * 3072 + c8g, &Qb[0][slot1 * 8]);
    glds16(vp + (size_t)r0 * 2048 + c8g, &Vb[0][slot0 * 8]);
    glds16(vp + (size_t)r1 * 2048 + c8g, &Vb[0][slot1 * 8]);
    __syncthreads();

    for (int jj = 0; jj < nj; ++jj) {
        const int cur = jj & 1;
        if (jj + 1 < nj) {              // async-prefetch next tile
            const int jn = (jj + 1) * 64;
            const int nb = cur ^ 1;
            glds16(qp + (size_t)(jn + r0) * 3072 + c8g, &Qb[nb][slot0 * 8]);
            glds16(qp + (size_t)(jn + r1) * 3072 + c8g, &Qb[nb][slot1 * 8]);
            glds16(vp + (size_t)r0 * 2048 + jn + c8g, &Vb[nb][slot0 * 8]);
            glds16(vp + (size_t)r1 * 2048 + jn + c8g, &Vb[nb][slot1 * 8]);
        }
        const int j0 = jj * 64;

        // S^T[j][i]: A = Q rows j (4 jt), B = kf (wave's 16 i-rows)
        bf16x8 qf[4][2];
        #pragma unroll
        for (int jt = 0; jt < 4; ++jt)
            #pragma unroll
            for (int kt = 0; kt < 2; ++kt)
                qf[jt][kt] = *(const bf16x8*)&Qb[cur][(jt * 16 + c) * 64 + (((kt * 4 + qd) ^ swz) << 3)];
        f32x4 sacc[4];
        #pragma unroll
        for (int jt = 0; jt < 4; ++jt) {
            f32x4 s0 = zero4;
            s0 = MFMA_BF16(qf[jt][0], kf[0], s0);
            s0 = MFMA_BF16(qf[jt][1], kf[1], s0);
            sacc[jt] = s0;
        }

        if (j0 + 63 > iw) {   // causal: valid iff j <= i
            #pragma unroll
            for (int jt = 0; jt < 4; ++jt)
                #pragma unroll
                for (int r = 0; r < 4; ++r) {
                    int j = j0 + jt * 16 + qd * 4 + r;
                    int i = iw + c;
                    if (j > i) sacc[jt][r] = -3.0e38f;
                }
        }

        // static-max softmax; pack P via round-half-up + v_perm (3 ops / 2 vals)
        #pragma unroll
        for (int jt = 0; jt < 4; ++jt) {
            float p0 = exp2f(sacc[jt][0]);
            float p1 = exp2f(sacc[jt][1]);
            float p2 = exp2f(sacc[jt][2]);
            float p3 = exp2f(sacc[jt][3]);
            l_lane += (p0 + p1) + (p2 + p3);
            u32 b0, b1, b2, b3;
            __builtin_memcpy(&b0, &p0, 4);
            __builtin_memcpy(&b1, &p1, 4);
            __builtin_memcpy(&b2, &p2, 4);
            __builtin_memcpy(&b3, &p3, 4);
            uint2 pk;
            pk.x = __builtin_amdgcn_perm(b1 + 0x8000u, b0 + 0x8000u, 0x07060302u);
            pk.y = __builtin_amdgcn_perm(b3 + 0x8000u, b2 + 0x8000u, 0x07060302u);
            *(uint2*)&Ps[w][c * 72 + jt * 16 + qd * 4] = pk;
        }

        // O[i][d] += P[i][j] * V[j][d]
        #pragma unroll
        for (int kt = 0; kt < 2; ++kt) {
            bf16x8 pf = *(const bf16x8*)&Ps[w][c * 72 + kt * 32 + qd * 8];
            #pragma unroll
            for (int nt = 0; nt < 4; ++nt) {
                bf16x8 vf = *(const bf16x8*)&Vb[cur][(nt * 16 + c) * 64 + (((kt * 4 + qd) ^ swz) << 3)];
                oacc[nt] = MFMA_BF16(pf, vf, oacc[nt]);
            }
        }
        __syncthreads();   // drains prefetch glds; all reads of cur done
    }

    // epilogue: reduce l over qd, redistribute per-row, write out
    float l = l_lane;
    l += __shfl_xor(l, 16);
    l += __shfl_xor(l, 32);
    red[w][c] = l;
    #pragma unroll
    for (int r = 0; r < 4; ++r) {
        const int irow = iw + qd * 4 + r;
        const float inv = 1.0f / red[w][qd * 4 + r];
        #pragma unroll
        for (int nt = 0; nt < 4; ++nt)
            op[(size_t)irow * 1024 + nt * 16 + c] = f2bf(oacc[nt][r] * inv);
    }
}

// ---------------------------------------------------------------------------
// ws plan (peak 40 MiB):
//   kqv@0 (24M, natural [4096][3072] bf16)  vtr@24M (8M)
//   wt_attn@32M (6M, dead after gemm_qkv)  abuf@32M (8M, after wt_attn dead)
//   wt_proj@0 (2M, kqv dead after attn)
//   xb (bf16 x) staged in d_out (f32 out = 16 MB); dead before proj gemm.
// ---------------------------------------------------------------------------
extern "C" void kernel_launch(void* const* d_in, const int* in_sizes, int n_in,
                              void* d_out, int out_size, void* d_ws, size_t ws_size,
                              hipStream_t stream) {
    const void *px = nullptr, *paw = nullptr, *pab = nullptr, *ppw = nullptr, *ppb = nullptr;
    for (int i = 0; i < n_in; ++i) {
        switch (in_sizes[i]) {
            case 4194304: px  = d_in[i]; break;  // x [2,2048,1024] f32
            case 3145728: paw = d_in[i]; break;  // c_attn_w [1024,3072] f32
            case 3072:    pab = d_in[i]; break;  // c_attn_b f32
            case 1048576: ppw = d_in[i]; break;  // c_proj_w [1024,1024] f32
            case 1024:    ppb = d_in[i]; break;  // c_proj_b f32
        }
    }
    if (!px || !paw || !pab || !ppw || !ppb) return;

    char* ws = (char*)d_ws;
    u16* kqv     = (u16*)(ws);                 // [4096,3072] bf16  24 MB
    u16* vtr     = (u16*)(ws + 25165824);      // [2,16,64,2048]     8 MB
    u16* wt_attn = (u16*)(ws + 33554432);      // [3072,1024]        6 MB
    u16* abuf    = (u16*)(ws + 33554432);      // [4096,1024] bf16   8 MB (wt_attn dead)
    u16* wt_proj = (u16*)(ws);                 // [1024,1024]        2 MB (kqv dead)
    float* out   = (float*)d_out;              // [4096,1024] f32
    u16* xb      = (u16*)d_out;                // bf16 x staged in d_out

    f32_to_bf16<<<2048, 256, 0, stream>>>((const float*)px, xb);
    transpose_k<<<dim3(48, 16), 256, 0, stream>>>((const float*)paw, wt_attn, 1024, 3072);
    gemm_qkv<<<dim3(32, 24), 256, 0, stream>>>(xb, wt_attn, (const float*)pab, kqv);
    transpose_v<<<dim3(32, 32), 256, 0, stream>>>(kqv, vtr);
    attn_kernel<<<dim3(1024), 256, 0, stream>>>(kqv, vtr, abuf);
    transpose_k<<<dim3(16, 16), 256, 0, stream>>>((const float*)ppw, wt_proj, 1024, 1024);
    gemm_proj<<<dim3(32, 16), 256, 0, stream>>>(abuf, wt_proj, (const float*)ppb, out);
}